// Round 6
// baseline (13.468 us; speedup 1.0000x reference)
//
#include <hip/hip_runtime.h>

// DuplicateByDuration, fused, LDS-gather version.
// y[b,c,j] = x[b,c,i(b,j)] * x_mask[b,i] * y_mask[b,j]; i(b,j) = token whose
// cumulative-duration interval contains frame j; 0 past total duration.
// B=16, C=192, T_TEXT=512, T_FEAT=2048, w in [0,8).
//
// Grid = 16 batches x 16 channel-tiles = 256 blocks of 1024 threads.
// x rows are staged in LDS pre-multiplied by x_mask, padded with a zero
// sentinel at index 512; sidx defaults to 512 so invalid frames gather 0.

#define BB 16
#define CC 192
#define T_TEXT 512
#define T_FEAT 2048
#define CH_TILE 12
#define NTILES (CC / CH_TILE)   // 16
#define NTHREADS 1024
#define SXROW 513               // padded row stride; sx[c][512] == 0

__global__ __launch_bounds__(NTHREADS) void dup_by_dur_fused(
    const float* __restrict__ x, const int* __restrict__ w,
    const float* __restrict__ x_mask, const float* __restrict__ y_mask,
    float* __restrict__ out)
{
    const int t    = threadIdx.x;
    const int lane = t & 63;
    const int wv   = t >> 6;            // waves 0..7 own tokens
    const int b    = blockIdx.x >> 4;
    const int tile = blockIdx.x & 15;
    const int cglob0 = tile * CH_TILE;

    __shared__ int   wtot[16];
    __shared__ float sxm_tok[T_TEXT];      // x_mask per token
    __shared__ short sidx[T_FEAT];         // frame -> token (512 = invalid)
    __shared__ float sx[CH_TILE * SXROW];  // x*xm rows, zero-padded

    // ---- early global loads (latency hides under scan) ----
    // stage task A: rows 0..7 (all threads); task B: rows 8..11 (t < 512)
    const int cA = t >> 7, iA = (t & 127) * 4;
    const float4 xa = *(const float4*)(x + ((size_t)b * CC + cglob0 + cA) * T_TEXT + iA);
    const int qB = t + NTHREADS;
    const int cB = qB >> 7, iB = (qB & 127) * 4;
    float4 xb = float4{0.f, 0.f, 0.f, 0.f};
    if (t < 512)
        xb = *(const float4*)(x + ((size_t)b * CC + cglob0 + cB) * T_TEXT + iB);
    const float4 ym = *(const float4*)(y_mask + (size_t)b * T_FEAT + 4 * (t & 511));

    int wm = 0; float xm = 0.f;
    if (t < T_TEXT) {
        float wf = (float)w[b * T_TEXT + t];
        xm = x_mask[b * T_TEXT + t];
        wm = (int)(wf * xm);             // reference truncation semantics
        sxm_tok[t] = xm;
    }

    // init sidx to sentinel 512 (2 shorts per thread covers all 2048)
    *(int*)(sidx + 2 * t) = 0x02000200;

    // ---- register wave scan of durations ----
    int p = wm;
    #pragma unroll
    for (int off = 1; off < 64; off <<= 1) {
        int v = __shfl_up(p, off);
        if (lane >= off) p += v;
    }
    if (lane == 63) wtot[wv] = p;
    __syncthreads();                     // covers sidx init, sxm_tok, wtot

    // ---- stage x * x_mask into LDS ----
    {
        const float4 mA = *(const float4*)(sxm_tok + iA);
        float4 v = xa;
        v.x *= mA.x; v.y *= mA.y; v.z *= mA.z; v.w *= mA.w;
        *(float4*)(sx + cA * SXROW + iA) = v;
        if (t < 512) {
            const float4 mB = *(const float4*)(sxm_tok + iB);
            float4 u = xb;
            u.x *= mB.x; u.y *= mB.y; u.z *= mB.z; u.w *= mB.w;
            *(float4*)(sx + cB * SXROW + iB) = u;
        }
        if (t < CH_TILE) sx[t * SXROW + 512] = 0.f;   // zero sentinel per row
    }

    // ---- scatter own token's frame range (disjoint across threads) ----
    if (t < T_TEXT) {
        int prefix = 0;
        #pragma unroll
        for (int k = 0; k < T_TEXT / 64; ++k)
            if (k < wv) prefix += wtot[k];
        int end   = prefix + p;          // cum[t]
        int start = end - wm;
        start = min(start, T_FEAT);
        end   = min(end, T_FEAT);
        for (int j = start; j < end; ++j) sidx[j] = (short)t;
    }
    __syncthreads();

    // ---- gather from LDS + stream out ----
    const int j  = 4 * (t & 511);
    const int ch = t >> 9;               // 0 or 1
    const short4 i4 = *(const short4*)(sidx + j);
    const int o0 = (int)i4.x, o1 = (int)i4.y, o2 = (int)i4.z, o3 = (int)i4.w;

    #pragma unroll
    for (int k = 0; k < CH_TILE / 2; ++k) {
        const int c = 2 * k + ch;
        const float* __restrict__ row = sx + c * SXROW;
        float4 o;
        o.x = row[o0] * ym.x;
        o.y = row[o1] * ym.y;
        o.z = row[o2] * ym.z;
        o.w = row[o3] * ym.w;
        *(float4*)(out + ((size_t)b * CC + cglob0 + c) * T_FEAT + j) = o;
    }
}

extern "C" void kernel_launch(void* const* d_in, const int* in_sizes, int n_in,
                              void* d_out, int out_size, void* d_ws, size_t ws_size,
                              hipStream_t stream) {
    const float* x      = (const float*)d_in[0];
    const int*   w      = (const int*)d_in[1];
    const float* x_mask = (const float*)d_in[2];
    const float* y_mask = (const float*)d_in[3];
    float* out = (float*)d_out;

    dup_by_dur_fused<<<BB * NTILES, NTHREADS, 0, stream>>>(x, w, x_mask, y_mask, out);
}